// Round 1
// baseline (5234.298 us; speedup 1.0000x reference)
//
#include <hip/hip_runtime.h>

#define WAVE 64

// ---------------------------------------------------------------------------
// split pointcloud (B,N,6) -> xyz (B,N,3) + feats (B,N,3)
__global__ __launch_bounds__(256) void split_kernel(const float* __restrict__ pc,
    float* __restrict__ xyz, float* __restrict__ feats, int total) {
  int t = blockIdx.x * blockDim.x + threadIdx.x;
  if (t >= total) return;
  const float* p = pc + (size_t)t * 6;
  xyz[t * 3 + 0] = p[0]; xyz[t * 3 + 1] = p[1]; xyz[t * 3 + 2] = p[2];
  feats[t * 3 + 0] = p[3]; feats[t * 3 + 1] = p[4]; feats[t * 3 + 2] = p[5];
}

__global__ __launch_bounds__(256) void zero_kernel(float* __restrict__ p, int n) {
  int t = blockIdx.x * blockDim.x + threadIdx.x;
  if (t < n) p[t] = 0.f;
}

// ---------------------------------------------------------------------------
// Farthest point sampling, one block per batch. Points held in registers.
// Exact rounding: ((dx*dx + dy*dy) + dz*dz) with explicit _rn ops (no FMA
// contraction) so mind values are bit-identical to the numpy reference;
// argmax tie-break = smallest index (first occurrence, like jnp.argmax).
// Emits the selected point coords (the reference records `last` BEFORE the
// update, so index 0 is always first).
template<int P>
__global__ __launch_bounds__(1024) void fps_kernel(const float* __restrict__ xyz,
    float* __restrict__ new_xyz, int N, int S) {
  const int b = blockIdx.x;
  const int T = blockDim.x;
  const int tid = threadIdx.x;
  const float* px = xyz + (size_t)b * N * 3;
  float rx[P], ry[P], rz[P], mind[P];
#pragma unroll
  for (int p = 0; p < P; ++p) {
    int i = tid + p * T;
    rx[p] = px[i * 3 + 0]; ry[p] = px[i * 3 + 1]; rz[p] = px[i * 3 + 2];
    mind[p] = 1e10f;
  }
  __shared__ unsigned long long s_wave[16];
  __shared__ float s_pt[3];
  const int nw = T >> 6;
  const int wv = tid >> 6;
  int last = 0;
  for (int it = 0; it < S; ++it) {
    if (tid == 0) {
      float qx = px[last * 3 + 0], qy = px[last * 3 + 1], qz = px[last * 3 + 2];
      s_pt[0] = qx; s_pt[1] = qy; s_pt[2] = qz;
      float* o = new_xyz + ((size_t)b * S + it) * 3;
      o[0] = qx; o[1] = qy; o[2] = qz;
    }
    __syncthreads();
    float qx = s_pt[0], qy = s_pt[1], qz = s_pt[2];
    float bestv = -1.f; int besti = 0;
#pragma unroll
    for (int p = 0; p < P; ++p) {
      float dx = __fsub_rn(rx[p], qx);
      float dy = __fsub_rn(ry[p], qy);
      float dz = __fsub_rn(rz[p], qz);
      float d = __fadd_rn(__fadd_rn(__fmul_rn(dx, dx), __fmul_rn(dy, dy)), __fmul_rn(dz, dz));
      float mo = fminf(mind[p], d);
      mind[p] = mo;
      // p ascending => index ascending within thread: keeps first max on ties
      if (mo > bestv) { bestv = mo; besti = tid + p * T; }
    }
    // pack (val, inverted idx): larger key = larger val, tie -> smaller index.
    // vals are >= 0 so float bits are order-preserving as u32.
    unsigned long long key = ((unsigned long long)__float_as_uint(bestv) << 32)
                           | (unsigned long long)(0xFFFFFFFFu - (unsigned)besti);
#pragma unroll
    for (int off = 1; off < 64; off <<= 1) {
      unsigned long long o = __shfl_xor(key, off, 64);
      if (o > key) key = o;
    }
    if ((tid & 63) == 0) s_wave[wv] = key;
    __syncthreads();
    unsigned long long k0 = s_wave[0];
    for (int w2 = 1; w2 < nw; ++w2) {
      unsigned long long o = s_wave[w2];
      if (o > k0) k0 = o;
    }
    last = (int)(0xFFFFFFFFu - (unsigned)(k0 & 0xFFFFFFFFull));
    // next write to s_wave/s_pt happens only after the first __syncthreads of
    // the next iteration, so no extra barrier needed here.
  }
}

// ---------------------------------------------------------------------------
// Ball query: one wave per center; take the FIRST nsample indices (ascending)
// with d2 < r2 (== nsample smallest indices, matching top_k(-key)). Pad with
// the first hit (0 if no hits).
__global__ __launch_bounds__(256) void ballquery_kernel(const float* __restrict__ xyz,
    const float* __restrict__ centers, int* __restrict__ out_idx,
    int N, int S, int nsample, float r2) {
  int gw = (blockIdx.x * blockDim.x + threadIdx.x) >> 6;
  int lane = threadIdx.x & 63;
  int b = gw / S;
  int s = gw - b * S;
  const float* px = xyz + (size_t)b * N * 3;
  const float* cp = centers + ((size_t)b * S + s) * 3;
  float cx = cp[0], cy = cp[1], cz = cp[2];
  int* out = out_idx + ((size_t)b * S + s) * nsample;
  int cnt = 0;
  int firsti = 0;
  for (int base = 0; base < N; base += WAVE) {
    int i = base + lane;
    float dx = __fsub_rn(cx, px[i * 3 + 0]);
    float dy = __fsub_rn(cy, px[i * 3 + 1]);
    float dz = __fsub_rn(cz, px[i * 3 + 2]);
    float d = __fadd_rn(__fadd_rn(__fmul_rn(dx, dx), __fmul_rn(dy, dy)), __fmul_rn(dz, dz));
    bool hit = d < r2;
    unsigned long long m = __ballot(hit);
    if (hit) {
      int slot = cnt + __popcll(m & ((1ull << lane) - 1ull));
      if (slot < nsample) out[slot] = i;
    }
    if (cnt == 0 && m) firsti = base + __ffsll((unsigned long long)m) - 1;
    cnt += __popcll(m);
    if (cnt >= nsample) break;
  }
  for (int q = cnt + lane; q < nsample; q += WAVE) out[q] = firsti;
}

// ---------------------------------------------------------------------------
// Build X0 rows: [xyz[j]-center (3), feats[j] (ci)] for r=(b,s,k), c in [0,3+ci)
__global__ __launch_bounds__(256) void group_kernel(const float* __restrict__ xyz,
    const float* __restrict__ feats, const float* __restrict__ centers,
    const int* __restrict__ idx, float* __restrict__ X,
    int N, int S, int K, int ci, int R) {
  int t = blockIdx.x * blockDim.x + threadIdx.x;
  int C0 = ci + 3;
  int r = t / C0;
  if (r >= R) return;
  int c = t - r * C0;
  int g = r / K;          // b*S + s
  int b = g / S;
  int j = idx[r];
  float v;
  if (c < 3) v = __fsub_rn(xyz[((size_t)b * N + j) * 3 + c], centers[(size_t)g * 3 + c]);
  else       v = feats[((size_t)b * N + j) * ci + (c - 3)];
  X[(size_t)r * C0 + c] = v;
}

// ---------------------------------------------------------------------------
// Tiled f32 GEMM: Y(RxCo) = X(RxC) @ W(CxCo). R % 64 == 0 always; C/Co guarded.
#define BM 64
#define BN 64
#define BK 16
__global__ __launch_bounds__(256) void mm_kernel(const float* __restrict__ A,
    const float* __restrict__ W, float* __restrict__ Y, int R, int C, int Co) {
  __shared__ float As[BK][BM + 4];
  __shared__ float Bs[BK][BN + 4];
  int r0 = blockIdx.x * BM;
  int n0 = blockIdx.y * BN;
  int tid = threadIdx.x;
  int tx = tid & 15, ty = tid >> 4;
  float acc[4][4] = {};
  for (int k0 = 0; k0 < C; k0 += BK) {
#pragma unroll
    for (int u = 0; u < 4; ++u) {
      int lin = tid + u * 256;
      int row = lin >> 4;
      int cc = lin & 15;
      int c = k0 + cc;
      As[cc][row] = (c < C) ? A[(size_t)(r0 + row) * C + c] : 0.f;
    }
#pragma unroll
    for (int u = 0; u < 4; ++u) {
      int lin = tid + u * 256;
      int kk = lin >> 6;
      int n = lin & 63;
      int c = k0 + kk;
      Bs[kk][n] = (c < C && (n0 + n) < Co) ? W[(size_t)c * Co + n0 + n] : 0.f;
    }
    __syncthreads();
#pragma unroll
    for (int kk = 0; kk < BK; ++kk) {
      float a0[4], b0[4];
#pragma unroll
      for (int i = 0; i < 4; ++i) a0[i] = As[kk][ty * 4 + i];
#pragma unroll
      for (int jj = 0; jj < 4; ++jj) b0[jj] = Bs[kk][tx * 4 + jj];
#pragma unroll
      for (int i = 0; i < 4; ++i)
#pragma unroll
        for (int jj = 0; jj < 4; ++jj)
          acc[i][jj] = fmaf(a0[i], b0[jj], acc[i][jj]);
    }
    __syncthreads();
  }
#pragma unroll
  for (int i = 0; i < 4; ++i) {
    int r = r0 + ty * 4 + i;
#pragma unroll
    for (int jj = 0; jj < 4; ++jj) {
      int n = n0 + tx * 4 + jj;
      if (n < Co) Y[(size_t)r * Co + n] = acc[i][jj];
    }
  }
}

// ---------------------------------------------------------------------------
// Per-channel sum / sumsq over R rows into st[0..Co) and st[512..512+Co).
__global__ __launch_bounds__(256) void stats_kernel(const float* __restrict__ Y,
    float* __restrict__ st, int R, int Co) {
  __shared__ float s_sum[512], s_sq[512];
  for (int i = threadIdx.x; i < Co; i += 256) { s_sum[i] = 0.f; s_sq[i] = 0.f; }
  __syncthreads();
  int r0 = blockIdx.x * 512;
  int r1 = min(R, r0 + 512);
  if (Co <= 256) {
    int c = threadIdx.x & (Co - 1);
    int rstep = 256 / Co;
    int roff = threadIdx.x / Co;
    float ls = 0.f, lq = 0.f;
    for (int r = r0 + roff; r < r1; r += rstep) {
      float v = Y[(size_t)r * Co + c];
      ls += v; lq += v * v;
    }
    atomicAdd(&s_sum[c], ls); atomicAdd(&s_sq[c], lq);
  } else {  // Co == 512
    int c = threadIdx.x;
    float ls = 0.f, lq = 0.f, ls2 = 0.f, lq2 = 0.f;
    for (int r = r0; r < r1; ++r) {
      float v = Y[(size_t)r * 512 + c];
      float v2 = Y[(size_t)r * 512 + c + 256];
      ls += v; lq += v * v; ls2 += v2; lq2 += v2 * v2;
    }
    atomicAdd(&s_sum[c], ls); atomicAdd(&s_sq[c], lq);
    atomicAdd(&s_sum[c + 256], ls2); atomicAdd(&s_sq[c + 256], lq2);
  }
  __syncthreads();
  for (int i = threadIdx.x; i < Co; i += 256) {
    atomicAdd(&st[i], s_sum[i]);
    atomicAdd(&st[512 + i], s_sq[i]);
  }
}

// ---------------------------------------------------------------------------
// x = relu(gamma*(y-mu)*rsqrt(var+eps)+beta), mu/var from sums. In-place safe.
__global__ __launch_bounds__(256) void norm_relu_kernel(const float* Y,
    float* O, const float* __restrict__ st,
    const float* __restrict__ gamma, const float* __restrict__ beta,
    int total, int Co, float inv_n) {
  int t = blockIdx.x * blockDim.x + threadIdx.x;
  if (t >= total) return;
  int c = t & (Co - 1);
  float mu = st[c] * inv_n;
  float var = st[512 + c] * inv_n - mu * mu;
  float rs = rsqrtf(var + 1e-5f);
  float v = gamma[c] * ((Y[t] - mu) * rs) + beta[c];
  O[t] = v > 0.f ? v : 0.f;
}

// Last sub-layer: normalize+relu then max over the K samples of each group.
__global__ __launch_bounds__(256) void norm_relu_max_kernel(const float* __restrict__ Y,
    float* __restrict__ O, const float* __restrict__ st,
    const float* __restrict__ gamma, const float* __restrict__ beta,
    int G, int K, int Co, float inv_n) {
  int t = blockIdx.x * blockDim.x + threadIdx.x;
  if (t >= G * Co) return;
  int c = t & (Co - 1);
  int g = t / Co;
  float mu = st[c] * inv_n;
  float var = st[512 + c] * inv_n - mu * mu;
  float rs = rsqrtf(var + 1e-5f);
  float ga = gamma[c], be = beta[c];
  const float* yp = Y + (size_t)g * K * Co + c;
  float m = -1e30f;
  for (int k = 0; k < K; ++k) {
    float v = ga * ((yp[(size_t)k * Co] - mu) * rs) + be;
    m = fmaxf(m, v);
  }
  O[t] = m > 0.f ? m : 0.f;
}

// ---------------------------------------------------------------------------
extern "C" void kernel_launch(void* const* d_in, const int* in_sizes, int n_in,
                              void* d_out, int out_size, void* d_ws, size_t ws_size,
                              hipStream_t stream) {
  const float* pc = (const float*)d_in[0];
  float* out = (float*)d_out;
  char* wsb = (char*)d_ws;

  // ws layout: [0,1MB) ball idx; [1MB,1MB+48KB) stats; [2MB,36MB) bufA; [36MB,104MB) bufB
  int* ballidx = (int*)wsb;
  float* stats = (float*)(wsb + ((size_t)1 << 20));
  float* bufA = (float*)(wsb + ((size_t)2 << 20));
  float* bufB = (float*)(wsb + ((size_t)36 << 20));

  const int B = 8;
  static const int Ns[4] = {16384, 1024, 256, 64};
  static const int Ss[4] = {1024, 256, 64, 16};
  static const int Ks[4] = {32, 32, 16, 16};
  static const double Rr[4] = {0.02, 0.04, 0.06, 0.08};
  static const int Ci[4] = {3, 64, 128, 256};
  static const int mlp[4][4] = {{6,32,32,64},{67,64,64,128},{131,128,128,256},{259,256,256,512}};
  static const size_t ox[5] = {0, 393216, 417792, 423936, 425472};
  static const size_t of[5] = {425856, 819072, 1343360, 1605504, 1736576};

  split_kernel<<<(B * 16384 + 255) / 256, 256, 0, stream>>>(pc, out + ox[0], out + of[0], B * 16384);
  zero_kernel<<<(12 * 1024 + 255) / 256, 256, 0, stream>>>(stats, 12 * 1024);

  for (int l = 0; l < 4; ++l) {
    const float* xyz = out + ox[l];
    const float* fts = out + of[l];
    float* nxyz = out + ox[l + 1];
    const int N = Ns[l], S = Ss[l], K = Ks[l], ci = Ci[l], C0 = ci + 3;
    const float r2 = (float)(Rr[l] * Rr[l]);

    if (l == 0) fps_kernel<16><<<B, 1024, 0, stream>>>(xyz, nxyz, N, S);
    else        fps_kernel<1><<<B, N, 0, stream>>>(xyz, nxyz, N, S);

    ballquery_kernel<<<(B * S) / 4, 256, 0, stream>>>(xyz, nxyz, ballidx, N, S, K, r2);

    const int R = B * S * K;
    {
      int total = R * C0;
      group_kernel<<<(total + 255) / 256, 256, 0, stream>>>(xyz, fts, nxyz, ballidx, bufA,
                                                            N, S, K, ci, R);
    }

    float* X = bufA; float* Y = bufB;
    for (int j = 0; j < 3; ++j) {
      const int cin = mlp[l][j], cout = mlp[l][j + 1];
      const float* Wt = (const float*)d_in[1 + (l * 3 + j) * 3 + 0];
      const float* Ga = (const float*)d_in[1 + (l * 3 + j) * 3 + 1];
      const float* Be = (const float*)d_in[1 + (l * 3 + j) * 3 + 2];
      dim3 grid(R / 64, (cout + 63) / 64);
      mm_kernel<<<grid, 256, 0, stream>>>(X, Wt, Y, R, cin, cout);
      float* st = stats + (size_t)(l * 3 + j) * 1024;
      stats_kernel<<<(R + 511) / 512, 256, 0, stream>>>(Y, st, R, cout);
      const float inv_n = 1.0f / (float)R;
      if (j < 2) {
        int tot = R * cout;
        norm_relu_kernel<<<(tot + 255) / 256, 256, 0, stream>>>(Y, Y, st, Ga, Be, tot, cout, inv_n);
        float* tswap = X; X = Y; Y = tswap;
      } else {
        int G = B * S;
        int tot = G * cout;
        norm_relu_max_kernel<<<(tot + 255) / 256, 256, 0, stream>>>(Y, out + of[l + 1], st, Ga, Be,
                                                                    G, K, cout, inv_n);
      }
    }
  }
}

// Round 2
// 3676.905 us; speedup vs baseline: 1.4236x; 1.4236x over previous
//
#include <hip/hip_runtime.h>

#define WAVE 64

// ---------------------------------------------------------------------------
// split pointcloud (B,N,6) -> xyz (B,N,3) + feats (B,N,3)
__global__ __launch_bounds__(256) void split_kernel(const float* __restrict__ pc,
    float* __restrict__ xyz, float* __restrict__ feats, int total) {
  int t = blockIdx.x * blockDim.x + threadIdx.x;
  if (t >= total) return;
  const float* p = pc + (size_t)t * 6;
  xyz[t * 3 + 0] = p[0]; xyz[t * 3 + 1] = p[1]; xyz[t * 3 + 2] = p[2];
  feats[t * 3 + 0] = p[3]; feats[t * 3 + 1] = p[4]; feats[t * 3 + 2] = p[5];
}

__global__ __launch_bounds__(256) void zero_kernel(float* __restrict__ p, int n) {
  int t = blockIdx.x * blockDim.x + threadIdx.x;
  if (t < n) p[t] = 0.f;
}

// ---------------------------------------------------------------------------
// Farthest point sampling, one block per batch. Points held in registers.
// __launch_bounds__(1024, 4): 1024-thread block = 4 waves/EU -> 128-VGPR cap.
// Without the 2nd arg the backend targeted higher occupancy, capped at ~56
// VGPRs and SPILLED the rx/ry/rz/mind arrays to scratch (round-1 counters:
// VGPR_Count=56 < 64 floats of state; 3.09 ms for layer 0).
// Exact rounding: ((dx*dx + dy*dy) + dz*dz) with explicit _rn ops (no FMA
// contraction); argmax tie-break = smallest index (first occurrence).
// Reduction: per-wave u64 butterfly -> wave0 reduces the <=16 wave winners
// (4-step shuffle) -> lane0 loads winning coords from global (single L2-hit
// load between barriers) -> LDS broadcast. Avoids the 1024-threads-scan-16-
// slots pattern of round 1 (~1500 cyc/iter of ds_read).
template<int P>
__global__ __launch_bounds__(1024, 4) void fps_kernel(const float* __restrict__ xyz,
    float* __restrict__ new_xyz, int N, int S) {
  const int b = blockIdx.x;
  const int T = blockDim.x;
  const int tid = threadIdx.x;
  const int lane = tid & 63;
  const int wv = tid >> 6;
  const int nw = T >> 6;
  const float* px = xyz + (size_t)b * N * 3;
  float rx[P], ry[P], rz[P], mind[P];
#pragma unroll
  for (int p = 0; p < P; ++p) {
    int i = tid + p * T;
    rx[p] = px[i * 3 + 0]; ry[p] = px[i * 3 + 1]; rz[p] = px[i * 3 + 2];
    mind[p] = 1e10f;
  }
  __shared__ unsigned long long s_wave[16];
  __shared__ float s_pt[3];
  // pick 0 is always index 0 (reference scan emits `last` before update)
  if (tid == 0) {
    float qx = px[0], qy = px[1], qz = px[2];
    s_pt[0] = qx; s_pt[1] = qy; s_pt[2] = qz;
    float* o = new_xyz + (size_t)b * S * 3;
    o[0] = qx; o[1] = qy; o[2] = qz;
  }
  __syncthreads();
  for (int it = 1; it < S; ++it) {
    float qx = s_pt[0], qy = s_pt[1], qz = s_pt[2];
    float bestv = -1.f; int besti = 0;
#pragma unroll
    for (int p = 0; p < P; ++p) {
      float dx = __fsub_rn(rx[p], qx);
      float dy = __fsub_rn(ry[p], qy);
      float dz = __fsub_rn(rz[p], qz);
      float d = __fadd_rn(__fadd_rn(__fmul_rn(dx, dx), __fmul_rn(dy, dy)), __fmul_rn(dz, dz));
      float mo = fminf(mind[p], d);
      mind[p] = mo;
      // p ascending => index ascending within thread: keeps first max on ties
      if (mo > bestv) { bestv = mo; besti = tid + p * T; }
    }
    // pack (val, inverted idx): larger key = larger val, tie -> smaller index.
    // vals are >= 0 so float bits are order-preserving as u32.
    unsigned long long key = ((unsigned long long)__float_as_uint(bestv) << 32)
                           | (unsigned long long)(0xFFFFFFFFu - (unsigned)besti);
#pragma unroll
    for (int off = 1; off < 64; off <<= 1) {
      unsigned long long o = __shfl_xor(key, off, 64);
      if (o > key) key = o;
    }
    if (lane == 0) s_wave[wv] = key;
    __syncthreads();
    if (wv == 0) {
      unsigned long long k = s_wave[lane < nw ? lane : 0];
#pragma unroll
      for (int off = 1; off < 16; off <<= 1) {
        unsigned long long o = __shfl_xor(k, off, 64);
        if (o > k) k = o;
      }
      if (lane == 0) {
        int last = (int)(0xFFFFFFFFu - (unsigned)(k & 0xFFFFFFFFull));
        const float* q = px + (size_t)last * 3;
        float nx = q[0], ny = q[1], nz = q[2];
        s_pt[0] = nx; s_pt[1] = ny; s_pt[2] = nz;
        float* o = new_xyz + ((size_t)b * S + it) * 3;
        o[0] = nx; o[1] = ny; o[2] = nz;
      }
    }
    __syncthreads();
  }
}

// ---------------------------------------------------------------------------
// Ball query: one wave per center; take the FIRST nsample indices (ascending)
// with d2 < r2 (== nsample smallest indices, matching top_k(-key)). Pad with
// the first hit (0 if no hits).
__global__ __launch_bounds__(256) void ballquery_kernel(const float* __restrict__ xyz,
    const float* __restrict__ centers, int* __restrict__ out_idx,
    int N, int S, int nsample, float r2) {
  int gw = (blockIdx.x * blockDim.x + threadIdx.x) >> 6;
  int lane = threadIdx.x & 63;
  int b = gw / S;
  int s = gw - b * S;
  const float* px = xyz + (size_t)b * N * 3;
  const float* cp = centers + ((size_t)b * S + s) * 3;
  float cx = cp[0], cy = cp[1], cz = cp[2];
  int* out = out_idx + ((size_t)b * S + s) * nsample;
  int cnt = 0;
  int firsti = 0;
  for (int base = 0; base < N; base += WAVE) {
    int i = base + lane;
    float dx = __fsub_rn(cx, px[i * 3 + 0]);
    float dy = __fsub_rn(cy, px[i * 3 + 1]);
    float dz = __fsub_rn(cz, px[i * 3 + 2]);
    float d = __fadd_rn(__fadd_rn(__fmul_rn(dx, dx), __fmul_rn(dy, dy)), __fmul_rn(dz, dz));
    bool hit = d < r2;
    unsigned long long m = __ballot(hit);
    if (hit) {
      int slot = cnt + __popcll(m & ((1ull << lane) - 1ull));
      if (slot < nsample) out[slot] = i;
    }
    if (cnt == 0 && m) firsti = base + __ffsll((unsigned long long)m) - 1;
    cnt += __popcll(m);
    if (cnt >= nsample) break;
  }
  for (int q = cnt + lane; q < nsample; q += WAVE) out[q] = firsti;
}

// ---------------------------------------------------------------------------
// Build X0 rows: [xyz[j]-center (3), feats[j] (ci)] for r=(b,s,k), c in [0,3+ci)
__global__ __launch_bounds__(256) void group_kernel(const float* __restrict__ xyz,
    const float* __restrict__ feats, const float* __restrict__ centers,
    const int* __restrict__ idx, float* __restrict__ X,
    int N, int S, int K, int ci, int R) {
  int t = blockIdx.x * blockDim.x + threadIdx.x;
  int C0 = ci + 3;
  int r = t / C0;
  if (r >= R) return;
  int c = t - r * C0;
  int g = r / K;          // b*S + s
  int b = g / S;
  int j = idx[r];
  float v;
  if (c < 3) v = __fsub_rn(xyz[((size_t)b * N + j) * 3 + c], centers[(size_t)g * 3 + c]);
  else       v = feats[((size_t)b * N + j) * ci + (c - 3)];
  X[(size_t)r * C0 + c] = v;
}

// ---------------------------------------------------------------------------
// Tiled f32 GEMM: Y(RxCo) = X(RxC) @ W(CxCo). R % 64 == 0 always; C/Co guarded.
#define BM 64
#define BN 64
#define BK 16
__global__ __launch_bounds__(256) void mm_kernel(const float* __restrict__ A,
    const float* __restrict__ W, float* __restrict__ Y, int R, int C, int Co) {
  __shared__ float As[BK][BM + 4];
  __shared__ float Bs[BK][BN + 4];
  int r0 = blockIdx.x * BM;
  int n0 = blockIdx.y * BN;
  int tid = threadIdx.x;
  int tx = tid & 15, ty = tid >> 4;
  float acc[4][4] = {};
  for (int k0 = 0; k0 < C; k0 += BK) {
#pragma unroll
    for (int u = 0; u < 4; ++u) {
      int lin = tid + u * 256;
      int row = lin >> 4;
      int cc = lin & 15;
      int c = k0 + cc;
      As[cc][row] = (c < C) ? A[(size_t)(r0 + row) * C + c] : 0.f;
    }
#pragma unroll
    for (int u = 0; u < 4; ++u) {
      int lin = tid + u * 256;
      int kk = lin >> 6;
      int n = lin & 63;
      int c = k0 + kk;
      Bs[kk][n] = (c < C && (n0 + n) < Co) ? W[(size_t)c * Co + n0 + n] : 0.f;
    }
    __syncthreads();
#pragma unroll
    for (int kk = 0; kk < BK; ++kk) {
      float a0[4], b0[4];
#pragma unroll
      for (int i = 0; i < 4; ++i) a0[i] = As[kk][ty * 4 + i];
#pragma unroll
      for (int jj = 0; jj < 4; ++jj) b0[jj] = Bs[kk][tx * 4 + jj];
#pragma unroll
      for (int i = 0; i < 4; ++i)
#pragma unroll
        for (int jj = 0; jj < 4; ++jj)
          acc[i][jj] = fmaf(a0[i], b0[jj], acc[i][jj]);
    }
    __syncthreads();
  }
#pragma unroll
  for (int i = 0; i < 4; ++i) {
    int r = r0 + ty * 4 + i;
#pragma unroll
    for (int jj = 0; jj < 4; ++jj) {
      int n = n0 + tx * 4 + jj;
      if (n < Co) Y[(size_t)r * Co + n] = acc[i][jj];
    }
  }
}

// ---------------------------------------------------------------------------
// Per-channel sum / sumsq over R rows into st[0..Co) and st[512..512+Co).
__global__ __launch_bounds__(256) void stats_kernel(const float* __restrict__ Y,
    float* __restrict__ st, int R, int Co) {
  __shared__ float s_sum[512], s_sq[512];
  for (int i = threadIdx.x; i < Co; i += 256) { s_sum[i] = 0.f; s_sq[i] = 0.f; }
  __syncthreads();
  int r0 = blockIdx.x * 512;
  int r1 = min(R, r0 + 512);
  if (Co <= 256) {
    int c = threadIdx.x & (Co - 1);
    int rstep = 256 / Co;
    int roff = threadIdx.x / Co;
    float ls = 0.f, lq = 0.f;
    for (int r = r0 + roff; r < r1; r += rstep) {
      float v = Y[(size_t)r * Co + c];
      ls += v; lq += v * v;
    }
    atomicAdd(&s_sum[c], ls); atomicAdd(&s_sq[c], lq);
  } else {  // Co == 512
    int c = threadIdx.x;
    float ls = 0.f, lq = 0.f, ls2 = 0.f, lq2 = 0.f;
    for (int r = r0; r < r1; ++r) {
      float v = Y[(size_t)r * 512 + c];
      float v2 = Y[(size_t)r * 512 + c + 256];
      ls += v; lq += v * v; ls2 += v2; lq2 += v2 * v2;
    }
    atomicAdd(&s_sum[c], ls); atomicAdd(&s_sq[c], lq);
    atomicAdd(&s_sum[c + 256], ls2); atomicAdd(&s_sq[c + 256], lq2);
  }
  __syncthreads();
  for (int i = threadIdx.x; i < Co; i += 256) {
    atomicAdd(&st[i], s_sum[i]);
    atomicAdd(&st[512 + i], s_sq[i]);
  }
}

// ---------------------------------------------------------------------------
// x = relu(gamma*(y-mu)*rsqrt(var+eps)+beta), mu/var from sums. In-place safe.
__global__ __launch_bounds__(256) void norm_relu_kernel(const float* Y,
    float* O, const float* __restrict__ st,
    const float* __restrict__ gamma, const float* __restrict__ beta,
    int total, int Co, float inv_n) {
  int t = blockIdx.x * blockDim.x + threadIdx.x;
  if (t >= total) return;
  int c = t & (Co - 1);
  float mu = st[c] * inv_n;
  float var = st[512 + c] * inv_n - mu * mu;
  float rs = rsqrtf(var + 1e-5f);
  float v = gamma[c] * ((Y[t] - mu) * rs) + beta[c];
  O[t] = v > 0.f ? v : 0.f;
}

// Last sub-layer: normalize+relu then max over the K samples of each group.
__global__ __launch_bounds__(256) void norm_relu_max_kernel(const float* __restrict__ Y,
    float* __restrict__ O, const float* __restrict__ st,
    const float* __restrict__ gamma, const float* __restrict__ beta,
    int G, int K, int Co, float inv_n) {
  int t = blockIdx.x * blockDim.x + threadIdx.x;
  if (t >= G * Co) return;
  int c = t & (Co - 1);
  int g = t / Co;
  float mu = st[c] * inv_n;
  float var = st[512 + c] * inv_n - mu * mu;
  float rs = rsqrtf(var + 1e-5f);
  float ga = gamma[c], be = beta[c];
  const float* yp = Y + (size_t)g * K * Co + c;
  float m = -1e30f;
  for (int k = 0; k < K; ++k) {
    float v = ga * ((yp[(size_t)k * Co] - mu) * rs) + be;
    m = fmaxf(m, v);
  }
  O[t] = m > 0.f ? m : 0.f;
}

// ---------------------------------------------------------------------------
extern "C" void kernel_launch(void* const* d_in, const int* in_sizes, int n_in,
                              void* d_out, int out_size, void* d_ws, size_t ws_size,
                              hipStream_t stream) {
  const float* pc = (const float*)d_in[0];
  float* out = (float*)d_out;
  char* wsb = (char*)d_ws;

  // ws layout: [0,1MB) ball idx; [1MB,1MB+48KB) stats; [2MB,36MB) bufA; [36MB,104MB) bufB
  int* ballidx = (int*)wsb;
  float* stats = (float*)(wsb + ((size_t)1 << 20));
  float* bufA = (float*)(wsb + ((size_t)2 << 20));
  float* bufB = (float*)(wsb + ((size_t)36 << 20));

  const int B = 8;
  static const int Ns[4] = {16384, 1024, 256, 64};
  static const int Ss[4] = {1024, 256, 64, 16};
  static const int Ks[4] = {32, 32, 16, 16};
  static const double Rr[4] = {0.02, 0.04, 0.06, 0.08};
  static const int Ci[4] = {3, 64, 128, 256};
  static const int mlp[4][4] = {{6,32,32,64},{67,64,64,128},{131,128,128,256},{259,256,256,512}};
  static const size_t ox[5] = {0, 393216, 417792, 423936, 425472};
  static const size_t of[5] = {425856, 819072, 1343360, 1605504, 1736576};

  split_kernel<<<(B * 16384 + 255) / 256, 256, 0, stream>>>(pc, out + ox[0], out + of[0], B * 16384);
  zero_kernel<<<(12 * 1024 + 255) / 256, 256, 0, stream>>>(stats, 12 * 1024);

  for (int l = 0; l < 4; ++l) {
    const float* xyz = out + ox[l];
    const float* fts = out + of[l];
    float* nxyz = out + ox[l + 1];
    const int N = Ns[l], S = Ss[l], K = Ks[l], ci = Ci[l], C0 = ci + 3;
    const float r2 = (float)(Rr[l] * Rr[l]);

    if (l == 0) fps_kernel<16><<<B, 1024, 0, stream>>>(xyz, nxyz, N, S);
    else        fps_kernel<1><<<B, N, 0, stream>>>(xyz, nxyz, N, S);

    ballquery_kernel<<<(B * S) / 4, 256, 0, stream>>>(xyz, nxyz, ballidx, N, S, K, r2);

    const int R = B * S * K;
    {
      int total = R * C0;
      group_kernel<<<(total + 255) / 256, 256, 0, stream>>>(xyz, fts, nxyz, ballidx, bufA,
                                                            N, S, K, ci, R);
    }

    float* X = bufA; float* Y = bufB;
    for (int j = 0; j < 3; ++j) {
      const int cin = mlp[l][j], cout = mlp[l][j + 1];
      const float* Wt = (const float*)d_in[1 + (l * 3 + j) * 3 + 0];
      const float* Ga = (const float*)d_in[1 + (l * 3 + j) * 3 + 1];
      const float* Be = (const float*)d_in[1 + (l * 3 + j) * 3 + 2];
      dim3 grid(R / 64, (cout + 63) / 64);
      mm_kernel<<<grid, 256, 0, stream>>>(X, Wt, Y, R, cin, cout);
      float* st = stats + (size_t)(l * 3 + j) * 1024;
      stats_kernel<<<(R + 511) / 512, 256, 0, stream>>>(Y, st, R, cout);
      const float inv_n = 1.0f / (float)R;
      if (j < 2) {
        int tot = R * cout;
        norm_relu_kernel<<<(tot + 255) / 256, 256, 0, stream>>>(Y, Y, st, Ga, Be, tot, cout, inv_n);
        float* tswap = X; X = Y; Y = tswap;
      } else {
        int G = B * S;
        int tot = G * cout;
        norm_relu_max_kernel<<<(tot + 255) / 256, 256, 0, stream>>>(Y, out + of[l + 1], st, Ga, Be,
                                                                    G, K, cout, inv_n);
      }
    }
  }
}